// Round 7
// baseline (344.275 us; speedup 1.0000x reference)
//
#include <hip/hip_runtime.h>
#include <hip/hip_bf16.h>

// Problem constants
#define TT 512   // T
#define BB 128   // B
#define HH 512   // H
#define NFC 128  // NF
// FS = 5

typedef short v8s __attribute__((ext_vector_type(8)));
typedef float v4f __attribute__((ext_vector_type(4)));

__device__ __forceinline__ unsigned short f2bf(float x) {
    unsigned u = __float_as_uint(x);
    unsigned r = (u + 0x7fffu + ((u >> 16) & 1u)) >> 16;
    return (unsigned short)r;
}

// ---------------------------------------------------------------------------
// Kernel 0: fused prep + gather.  (unchanged from r13)
// ---------------------------------------------------------------------------
__global__ void prep_all(const float* __restrict__ enc, const int* __restrict__ lengths,
                         unsigned short* __restrict__ Xg,
                         const float* __restrict__ w1, const float* __restrict__ w2,
                         const float* __restrict__ w3, const float* __restrict__ w4,
                         const float* __restrict__ w5, unsigned short* __restrict__ Wg,
                         float* __restrict__ pools,
                         const float* __restrict__ fc1w, const float* __restrict__ fc1b,
                         const float* __restrict__ fc2w, const float* __restrict__ fc2b,
                         float* __restrict__ v, int* __restrict__ wl) {
    int blk = blockIdx.x;
    int tid = threadIdx.x;
    if (blk < 8192) {
        __shared__ float tile[64 * 65];
        int b = blk >> 6;
        int lc = (blk >> 3) & 7;
        int hc = blk & 7;
        int L = lengths[b];
        int Leff = L > 5 ? L : 5;
        int l0 = lc * 64, h0 = hc * 64;
        if (l0 >= Leff + 127) return;     // never read by any active tile
        int lx = tid & 63;
        int hq = tid >> 6;                // 0..3
        #pragma unroll
        for (int r = 0; r < 16; ++r) {
            int hl = hq * 16 + r;         // local h
            int l = l0 + lx;
            float val = 0.f;
            if (l < L) {
                int i = (h0 + hl) * L + l;
                val = enc[(i >> 9) * (BB * HH) + b * HH + (i & 511)];
            }
            tile[hl * 65 + lx] = val;
        }
        __syncthreads();
        int hg = tid & 15;                // h quad within tile (4 bf16 = 8B)
        #pragma unroll
        for (int r = 0; r < 4; ++r) {
            int lloc = (tid >> 4) + r * 16;
            int n = b * 512 + l0 + lloc;
            ushort4 pk;
            pk.x = f2bf(tile[(hg * 4 + 0) * 65 + lloc]);
            pk.y = f2bf(tile[(hg * 4 + 1) * 65 + lloc]);
            pk.z = f2bf(tile[(hg * 4 + 2) * 65 + lloc]);
            pk.w = f2bf(tile[(hg * 4 + 3) * 65 + lloc]);
            *(ushort4*)&Xg[n * 512 + h0 + hg * 4] = pk;
        }
    } else if (blk < 12288) {
        int o = (blk - 8192) * 256 + tid;     // [0, 1,048,576)
        // fragment-order decomposition
        int j   = o & 7;
        int ln  = (o >> 3) & 63;
        int mi  = (o >> 9) & 3;
        int kt  = (o >> 11) & 15;
        int wmm = (o >> 15) & 1;
        int mtt = o >> 16;
        int row = mtt * 128 + wmm * 64 + mi * 16 + (ln & 15);   // 0..2047
        int k   = kt * 32 + (ln >> 4) * 8 + j;                  // 0..511
        int f = row >> 4, sl = row & 15;
        float val = 0.f;
        if (sl < 15) {
            int w, jj;
            if (sl < 1)       { w = 1; jj = sl; }
            else if (sl < 3)  { w = 2; jj = sl - 1; }
            else if (sl < 6)  { w = 3; jj = sl - 3; }
            else if (sl < 10) { w = 4; jj = sl - 6; }
            else              { w = 5; jj = sl - 10; }
            const float* wp = (w == 1) ? w1 : (w == 2) ? w2 : (w == 3) ? w3 : (w == 4) ? w4 : w5;
            val = wp[f * (HH * w) + k * w + jj];  // conv_w{w}[f,0,h=k,jj]
        }
        Wg[o] = f2bf(val);
    } else if (blk < 12608) {
        int i = (blk - 12288) * 256 + tid;
        if (i < BB * 5 * NFC) pools[i] = 0.f;
    } else if (blk == 12608) {
        for (int k = tid; k < 640; k += 256) {
            float s = 0.f;
            for (int o = 0; o < 100; ++o) s += fc2w[o] * fc1w[o * 640 + k];
            v[k] = s;
        }
        if (tid == 0) {
            float c = fc2b[0];
            for (int o = 0; o < 100; ++o) c += fc2w[o] * fc1b[o];
            v[640] = c;
        }
    } else {
        __shared__ int cnt;
        if (tid == 0) cnt = 0;
        __syncthreads();
        for (int it = tid; it < 640; it += 256) {
            int b = it / 5, tt = it % 5;
            int L = lengths[b];
            int Leff = L > 5 ? L : 5;
            int n0 = tt * 124 - ((tt >> 2) * 112);   // {0,124,248,372,384}
            if (n0 < Leff) {
                int pos = atomicAdd(&cnt, 1);
                wl[pos] = (b << 3) | tt;
            }
        }
        __syncthreads();
        if (tid == 0) wl[640] = cnt;
    }
}

// ---------------------------------------------------------------------------
// Kernel 1: main fused GEMM + epilogue.
// r18 = r16 envelope (launch_bounds (256,4), ring-4 x 8KB, 64 VGPR — the
// known-good register/LDS set; r17's (256,6) NaN'd from spilling inline-asm
// pending-load regs, and the reg file caps us at 4 blocks/CU anyway) with
// the K-loop restructured to BK=64: TWO 32-k subtiles per barrier.
// Per super-iter i (subtiles 2i,2i+1; 8 iters total):
//   vmcnt(8) ; barrier              -- drains Bs(2i),Bs(2i+1) (4 oldest)
//   stage Bs(2i+2),Bs(2i+3)         -- AFTER barrier: readers of those ring
//                                      slots (iter i-1) provably done
//   ds_read slot 2i ; vmcnt(8) ; sched_barrier -- drains A(2i)
//   16 MFMA (bankA) ; A-load bankA := A(2i+2)
//   ds_read slot 2i+1 ; vmcnt(8) ; sched_barrier -- drains A(2i+1)
//   16 MFMA (bankB) ; A-load bankB := A(2i+3)
// Steady-state queue is 12 outstanding at every wait -> uniform vmcnt(8);
// tail iter 7: no stage/loads, vmcnt 8/4/0. Barriers per block 16 -> 8:
// the ~450cy/kt sync overhead is amortized over 2x MFMA work.
// A-frag issue->wait distance ~1 super-iter (~1200cy). Slots read {sb,sb+1}
// and staged {2-sb,2-sb+1} are disjoint mod 4.
// Epilogue = r16 verbatim (2 phases of 64 rows, parallel butterflies).
// ---------------------------------------------------------------------------
#define GLDS(GP, LP) __builtin_amdgcn_global_load_lds(                            \
    (const __attribute__((address_space(1))) unsigned int*)(GP),                  \
    (__attribute__((address_space(3))) unsigned int*)(LP), 16, 0, 0)

#define LOADA4(B0, B1, B2, B3, PTR) do {                                          \
    asm volatile("global_load_dwordx4 %0, %1, off"             : "=v"(B0) : "v"(PTR) : "memory"); \
    asm volatile("global_load_dwordx4 %0, %1, off offset:1024" : "=v"(B1) : "v"(PTR) : "memory"); \
    asm volatile("global_load_dwordx4 %0, %1, off offset:2048" : "=v"(B2) : "v"(PTR) : "memory"); \
    asm volatile("global_load_dwordx4 %0, %1, off offset:3072" : "=v"(B3) : "v"(PTR) : "memory"); \
} while (0)

#define MFMA16(A0, A1, A2, A3) do {                                               \
    acc[0][0] = __builtin_amdgcn_mfma_f32_16x16x32_bf16(A0, Bf0, acc[0][0], 0, 0, 0); \
    acc[0][1] = __builtin_amdgcn_mfma_f32_16x16x32_bf16(A0, Bf1, acc[0][1], 0, 0, 0); \
    acc[0][2] = __builtin_amdgcn_mfma_f32_16x16x32_bf16(A0, Bf2, acc[0][2], 0, 0, 0); \
    acc[0][3] = __builtin_amdgcn_mfma_f32_16x16x32_bf16(A0, Bf3, acc[0][3], 0, 0, 0); \
    acc[1][0] = __builtin_amdgcn_mfma_f32_16x16x32_bf16(A1, Bf0, acc[1][0], 0, 0, 0); \
    acc[1][1] = __builtin_amdgcn_mfma_f32_16x16x32_bf16(A1, Bf1, acc[1][1], 0, 0, 0); \
    acc[1][2] = __builtin_amdgcn_mfma_f32_16x16x32_bf16(A1, Bf2, acc[1][2], 0, 0, 0); \
    acc[1][3] = __builtin_amdgcn_mfma_f32_16x16x32_bf16(A1, Bf3, acc[1][3], 0, 0, 0); \
    acc[2][0] = __builtin_amdgcn_mfma_f32_16x16x32_bf16(A2, Bf0, acc[2][0], 0, 0, 0); \
    acc[2][1] = __builtin_amdgcn_mfma_f32_16x16x32_bf16(A2, Bf1, acc[2][1], 0, 0, 0); \
    acc[2][2] = __builtin_amdgcn_mfma_f32_16x16x32_bf16(A2, Bf2, acc[2][2], 0, 0, 0); \
    acc[2][3] = __builtin_amdgcn_mfma_f32_16x16x32_bf16(A2, Bf3, acc[2][3], 0, 0, 0); \
    acc[3][0] = __builtin_amdgcn_mfma_f32_16x16x32_bf16(A3, Bf0, acc[3][0], 0, 0, 0); \
    acc[3][1] = __builtin_amdgcn_mfma_f32_16x16x32_bf16(A3, Bf1, acc[3][1], 0, 0, 0); \
    acc[3][2] = __builtin_amdgcn_mfma_f32_16x16x32_bf16(A3, Bf2, acc[3][2], 0, 0, 0); \
    acc[3][3] = __builtin_amdgcn_mfma_f32_16x16x32_bf16(A3, Bf3, acc[3][3], 0, 0, 0); \
} while (0)

#define BREAD(SLOT)                                                               \
    v8s Bf0 = *(const v8s*)&ldsB[(SLOT) * 4096 + (wn * 64 +  0 + llo) * 32 + psw * 8]; \
    v8s Bf1 = *(const v8s*)&ldsB[(SLOT) * 4096 + (wn * 64 + 16 + llo) * 32 + psw * 8]; \
    v8s Bf2 = *(const v8s*)&ldsB[(SLOT) * 4096 + (wn * 64 + 32 + llo) * 32 + psw * 8]; \
    v8s Bf3 = *(const v8s*)&ldsB[(SLOT) * 4096 + (wn * 64 + 48 + llo) * 32 + psw * 8];

__global__ __launch_bounds__(256, 4)
void conv_gemm(const unsigned short* __restrict__ Wg, const unsigned short* __restrict__ Xg,
               const int* __restrict__ lengths, const int* __restrict__ wl,
               const float* __restrict__ cb1, const float* __restrict__ cb2,
               const float* __restrict__ cb3, const float* __restrict__ cb4,
               const float* __restrict__ cb5,
               float* __restrict__ pools) {
    __shared__ __align__(16) char smem[33024];               // max(4x8KB B-ring, Gs)
    unsigned short* ldsB = (unsigned short*)smem;            // 4 slots x 4096 ushorts
    float* Gs = (float*)smem;                                // 64*129 floats (epilogue)

    int cnt = wl[640];
    // XCD-aligned decode (r15): siblings of one wl-position share g&7.
    int g = blockIdx.x;
    int xcd = g & 7;
    int q = g >> 3;
    int mt = q & 15;
    int wk = (q >> 4) * 8 + xcd;
    if (wk >= cnt) return;
    int item = wl[wk];
    int b = item >> 3, tt = item & 7;
    int n0 = tt * 124 - ((tt >> 2) * 112);   // {0,124,248,372,384}
    int L = lengths[b];
    int Leff = L > 5 ? L : 5;

    int tid = threadIdx.x;
    int wid = tid >> 6, lane = tid & 63;
    int wm = wid >> 1, wn = wid & 1;
    int llo = lane & 15, quad = lane >> 4;
    int psw = quad ^ ((llo >> 1) & 3);   // swizzled physical chunk for B frag reads

    int nb0 = b * 512 + n0;

    v4f acc[4][4];
    #pragma unroll
    for (int i = 0; i < 4; ++i)
        #pragma unroll
        for (int j = 0; j < 4; ++j) acc[i][j] = v4f{0.f, 0.f, 0.f, 0.f};

    // B staging: wave wid covers rows [wid*32, wid*32+32) in 2 insts of 16 rows
    int srow = lane >> 2;                           // 0..15
    int gchunk = (lane & 3) ^ ((lane >> 3) & 3);    // global chunk for physical slot lane&3
    const unsigned short* gB = Xg + (nb0 + wid * 32 + srow) * 512 + gchunk * 8;
    int sdst = (wid * 32) * 32;   // ushort offset of this wave's staging rows

    // A fragment stream: pre-swizzled Wg2, 16B/lane coalesced from L2.
    const unsigned short* pA = Wg + (mt * 2 + wm) * 32768 + lane * 8;

    // prologue (FIFO order = steady top-of-iter state): Bs0, Bs1, A0->bankA, A1->bankB
    GLDS(gB,                 &ldsB[0 * 4096 + sdst]);
    GLDS(gB + 16 * 512,      &ldsB[0 * 4096 + sdst + 512]);
    GLDS(gB + 32,            &ldsB[1 * 4096 + sdst]);
    GLDS(gB + 16 * 512 + 32, &ldsB[1 * 4096 + sdst + 512]);
    v8s AfA0, AfA1, AfA2, AfA3;   // bank A: even subtiles
    v8s AfB0, AfB1, AfB2, AfB3;   // bank B: odd  subtiles
    LOADA4(AfA0, AfA1, AfA2, AfA3, pA);
    {
        const unsigned short* pA1 = pA + 2048;
        LOADA4(AfB0, AfB1, AfB2, AfB3, pA1);
    }
    const unsigned short* pAc = pA + 4096;   // next = A(2)

    #pragma unroll 1
    for (int i = 0; i < 7; ++i) {
        int sb = (i & 1) * 2;        // read slots sb, sb+1
        int tb = 2 - sb;             // stage slots tb, tb+1
        asm volatile("s_waitcnt vmcnt(8)" ::: "memory");   // drains Bs(2i),Bs(2i+1)
        __builtin_amdgcn_s_barrier();
        // stage subtiles 2i+2, 2i+3 (after barrier: WAR-safe on ring half tb)
        {
            const unsigned short* gs = gB + (2 * i + 2) * 32;
            GLDS(gs,                 &ldsB[tb * 4096 + sdst]);
            GLDS(gs + 16 * 512,      &ldsB[tb * 4096 + sdst + 512]);
            GLDS(gs + 32,            &ldsB[(tb + 1) * 4096 + sdst]);
            GLDS(gs + 16 * 512 + 32, &ldsB[(tb + 1) * 4096 + sdst + 512]);
        }
        // ---- subphase a: subtile 2i, bank A ----
        {
            BREAD(sb);
            asm volatile("s_waitcnt vmcnt(8)" ::: "memory");   // drains A(2i)
            __builtin_amdgcn_sched_barrier(0);
            __builtin_amdgcn_s_setprio(1);
            MFMA16(AfA0, AfA1, AfA2, AfA3);
            __builtin_amdgcn_s_setprio(0);
            LOADA4(AfA0, AfA1, AfA2, AfA3, pAc);               // A(2i+2)
            pAc += 2048;
        }
        // ---- subphase b: subtile 2i+1, bank B ----
        {
            BREAD(sb + 1);
            asm volatile("s_waitcnt vmcnt(8)" ::: "memory");   // drains A(2i+1)
            __builtin_amdgcn_sched_barrier(0);
            __builtin_amdgcn_s_setprio(1);
            MFMA16(AfB0, AfB1, AfB2, AfB3);
            __builtin_amdgcn_s_setprio(0);
            LOADA4(AfB0, AfB1, AfB2, AfB3, pAc);               // A(2i+3)
            pAc += 2048;
        }
    }
    // ---- tail iter i=7: subtiles 14,15 in slots 2,3; no stage, no A-loads ----
    asm volatile("s_waitcnt vmcnt(8)" ::: "memory");           // drains Bs14,Bs15
    __builtin_amdgcn_s_barrier();
    {
        BREAD(2);
        asm volatile("s_waitcnt vmcnt(4)" ::: "memory");       // drains A(14)
        __builtin_amdgcn_sched_barrier(0);
        __builtin_amdgcn_s_setprio(1);
        MFMA16(AfA0, AfA1, AfA2, AfA3);
        __builtin_amdgcn_s_setprio(0);
    }
    {
        BREAD(3);
        asm volatile("s_waitcnt vmcnt(0)" ::: "memory");       // drains A(15)
        __builtin_amdgcn_sched_barrier(0);
        __builtin_amdgcn_s_setprio(1);
        MFMA16(AfB0, AfB1, AfB2, AfB3);
        __builtin_amdgcn_s_setprio(0);
    }

    __syncthreads();   // all waves done with B-ring before Gs overwrites smem

    // ---- epilogue: 2 phases of 64 rows (4 filter groups each) — r16 verbatim ----
    #pragma unroll
    for (int phase = 0; phase < 2; ++phase) {
        if (wm == phase) {
            // C/D layout: col = lane&15, row = quad*4 + reg  [verified m89/m91]
            #pragma unroll
            for (int mi = 0; mi < 4; ++mi)
                #pragma unroll
                for (int ni = 0; ni < 4; ++ni)
                    #pragma unroll
                    for (int r = 0; r < 4; ++r)
                        Gs[(mi * 16 + quad * 4 + r) * 129 + wn * 64 + ni * 16 + llo] = acc[mi][ni][r];
        }
        __syncthreads();
        {
            int fl = wid;
            int f = mt * 8 + phase * 4 + fl;
            float bias[5] = {cb1[f], cb2[f], cb3[f], cb4[f], cb5[f]};
            const int basew[5] = {0, 1, 3, 6, 10};
            const float* gbase = &Gs[(fl * 16) * 129 + lane];
            float vm[5];
            #pragma unroll
            for (int w = 1; w <= 5; ++w) {
                float s0 = 0.f, s1 = 0.f;
                #pragma unroll
                for (int j = 0; j < w; ++j) {
                    int o = basew[w - 1] * 129 + j * 130;
                    s0 += gbase[o];        // G[row+j][lane+j]
                    s1 += gbase[o + 64];   // G[row+j][lane+64+j]
                }
                int limv = Leff - w + 1 - n0;
                int lim = 128 - w; if (limv - 1 < lim) lim = limv - 1;
                float m = -1.f;
                if (lane <= lim)      m = fmaxf(m, fmaxf(s0 + bias[w - 1], 0.f));
                if (lane + 64 <= lim) m = fmaxf(m, fmaxf(s1 + bias[w - 1], 0.f));
                vm[w - 1] = m;
            }
            #pragma unroll
            for (int off = 32; off >= 1; off >>= 1) {
                #pragma unroll
                for (int w = 0; w < 5; ++w)
                    vm[w] = fmaxf(vm[w], __shfl_xor(vm[w], off));
            }
            if (lane == 0 && vm[0] >= 0.f) atomicMax((int*)&pools[(b * 5 + 0) * NFC + f], __float_as_int(vm[0]));
            if (lane == 1 && vm[1] >= 0.f) atomicMax((int*)&pools[(b * 5 + 1) * NFC + f], __float_as_int(vm[1]));
            if (lane == 2 && vm[2] >= 0.f) atomicMax((int*)&pools[(b * 5 + 2) * NFC + f], __float_as_int(vm[2]));
            if (lane == 3 && vm[3] >= 0.f) atomicMax((int*)&pools[(b * 5 + 3) * NFC + f], __float_as_int(vm[3]));
            if (lane == 4 && vm[4] >= 0.f) atomicMax((int*)&pools[(b * 5 + 4) * NFC + f], __float_as_int(vm[4]));
        }
        __syncthreads();
    }
}

// ---------------------------------------------------------------------------
// Kernel 2: per-batch dot(feat, v) + c -> sigmoid.  (unchanged)
// ---------------------------------------------------------------------------
__global__ void head(const float* __restrict__ pools, const float* __restrict__ v,
                     float* __restrict__ out) {
    int b = blockIdx.x;
    int tid = threadIdx.x;
    float s = 0.f;
    for (int k = tid; k < 640; k += 256) s += pools[b * 640 + k] * v[k];
    __shared__ float red[256];
    red[tid] = s;
    __syncthreads();
    for (int st = 128; st; st >>= 1) {
        if (tid < st) red[tid] += red[tid + st];
        __syncthreads();
    }
    if (tid == 0) out[b] = 1.f / (1.f + expf(-(red[0] + v[640])));
}

// ---------------------------------------------------------------------------
extern "C" void kernel_launch(void* const* d_in, const int* in_sizes, int n_in,
                              void* d_out, int out_size, void* d_ws, size_t ws_size,
                              hipStream_t stream) {
    const float* enc  = (const float*)d_in[0];
    const int* lens   = (const int*)d_in[1];
    const float* w1   = (const float*)d_in[2];
    const float* b1   = (const float*)d_in[3];
    const float* w2   = (const float*)d_in[4];
    const float* b2   = (const float*)d_in[5];
    const float* w3   = (const float*)d_in[6];
    const float* b3   = (const float*)d_in[7];
    const float* w4   = (const float*)d_in[8];
    const float* b4   = (const float*)d_in[9];
    const float* w5   = (const float*)d_in[10];
    const float* b5   = (const float*)d_in[11];
    const float* fc1w = (const float*)d_in[12];
    const float* fc1b = (const float*)d_in[13];
    const float* fc2w = (const float*)d_in[14];
    const float* fc2b = (const float*)d_in[15];
    float* out = (float*)d_out;

    // workspace layout
    unsigned short* Xg = (unsigned short*)d_ws;          // 33,554,432 ushorts (64 MB)
    unsigned short* Wg = Xg + 33554432;                  // 1,048,576 ushorts (2 MB, frag-order)
    float* pools  = (float*)(Wg + 1048576);              // 81,920 floats
    float* vbuf   = pools + 81920;                       // 641 floats
    int* wlist    = (int*)(vbuf + 641);                  // 641 ints

    prep_all<<<12610, 256, 0, stream>>>(enc, lens, Xg, w1, w2, w3, w4, w5, Wg, pools,
                                        fc1w, fc1b, fc2w, fc2b, vbuf, wlist);
    conv_gemm<<<10240, 256, 0, stream>>>(Wg, Xg, lens, wlist, b1, b2, b3, b4, b5, pools);
    head<<<128, 256, 0, stream>>>(pools, vbuf, out);
}